// Round 4
// baseline (1577.038 us; speedup 1.0000x reference)
//
#include <hip/hip_runtime.h>
#include <hip/hip_bf16.h>
#include <math.h>

typedef __hip_bfloat16 bf16;
typedef __attribute__((ext_vector_type(8))) short short8;
typedef __attribute__((ext_vector_type(4))) float f32x4;

#define D_  768
#define H_  12
#define HD_ 64
#define F_  3072
#define B_  4
#define S_  2048
#define BS_ (B_*S_)
#define SQK 1536   // Q,K buffer row stride (V lives in packed Vp)

__device__ __forceinline__ float b2f(bf16 x){ return __bfloat162float(x); }
__device__ __forceinline__ bf16  f2b(float x){ return __float2bfloat16(x); }

union BU { bf16 b; unsigned short u; };
__device__ __forceinline__ unsigned short f2bits(float x){ BU t; t.b = __float2bfloat16(x); return t.u; }

__device__ __forceinline__ f32x4 zero4(){ f32x4 z; z.x=0.f; z.y=0.f; z.z=0.f; z.w=0.f; return z; }

__device__ __forceinline__ f32x4 mfma16(uint4 a, uint4 b, f32x4 c){
  union U { uint4 u; short8 s; };
  U A, B; A.u = a; B.u = b;
  return __builtin_amdgcn_mfma_f32_16x16x32_bf16(A.s, B.s, c, 0, 0, 0);
}

// ---------------- weight repack (fp32 -> packed bf16): B[k][n] -> Bp[(k/8)*N + n][k&7]
__global__ __launch_bounds__(256)
void repack_plain(const float* __restrict__ B, bf16* __restrict__ Bp, int K, int N)
{
  const int t = blockIdx.x * 256 + threadIdx.x;     // exact grids, no bounds check
  const int n = t % N;
  const int kg = t / N;
  const float* src = B + (size_t)kg * 8 * N + n;
  union { unsigned short u16[8]; uint4 u; } pk;
#pragma unroll
  for (int j = 0; j < 8; ++j) pk.u16[j] = f2bits(src[(size_t)j * N]);
  *(uint4*)(Bp + (size_t)t * 8) = pk.u;
}

// QKV combined: logical B[k][n], n in [0,2304): sel=n/768 (Q,K,V), h=(n%768)>>6, e=n&63
__global__ __launch_bounds__(256)
void repack_qkv(const float* __restrict__ Wq, const float* __restrict__ Wk,
                const float* __restrict__ Wv, bf16* __restrict__ Bp)
{
  const int t = blockIdx.x * 256 + threadIdx.x;     // 96*2304 = 864*256 exact
  const int n = t % 2304;
  const int kg = t / 2304;
  const int sel = n / 768;
  const int nn = n - sel * 768;
  const int hh = nn >> 6;
  const int ee = nn & 63;
  const float* W = (sel == 0) ? Wq : (sel == 1) ? Wk : Wv;
  const float* src = W + ((size_t)hh * 768 + (size_t)kg * 8) * 64 + ee;
  union { unsigned short u16[8]; uint4 u; } pk;
#pragma unroll
  for (int j = 0; j < 8; ++j) pk.u16[j] = f2bits(src[(size_t)j * 64]);
  *(uint4*)(Bp + (size_t)t * 8) = pk.u;
}

__global__ __launch_bounds__(256)
void bias_qkv(const float* __restrict__ bq, const float* __restrict__ bk,
              const float* __restrict__ bv, float* __restrict__ out)
{
  const int t = blockIdx.x * 256 + threadIdx.x;     // 9*256 = 2304 exact
  out[t] = (t < 768) ? bq[t] : (t < 1536) ? bk[t - 768] : bv[t - 1536];
}

// ---------------- LayerNorm: one block per token, 256 thr, D=768=256*3 ----------------
__global__ __launch_bounds__(256)
void ln_x_kernel(const float* __restrict__ X, const float* __restrict__ G,
                 const float* __restrict__ Bet, bf16* __restrict__ Y)
{
  const int t = threadIdx.x;
  const size_t row = blockIdx.x;
  const float* x = X + row * D_;
  float v0 = x[t], v1 = x[t + 256], v2 = x[t + 512];
  float s = v0 + v1 + v2;
#pragma unroll
  for (int d = 32; d >= 1; d >>= 1) s += __shfl_xor(s, d, 64);
  __shared__ float red[8];
  const int wv = t >> 6, ln = t & 63;
  if (ln == 0) red[wv] = s;
  __syncthreads();
  const float mu = (red[0] + red[1] + red[2] + red[3]) * (1.0f / 768.0f);
  const float d0 = v0 - mu, d1 = v1 - mu, d2 = v2 - mu;
  float sq = d0 * d0 + d1 * d1 + d2 * d2;
#pragma unroll
  for (int d = 32; d >= 1; d >>= 1) sq += __shfl_xor(sq, d, 64);
  if (ln == 0) red[4 + wv] = sq;
  __syncthreads();
  const float var = (red[4] + red[5] + red[6] + red[7]) * (1.0f / 768.0f);
  const float rs = rsqrtf(var + 1e-5f);
  bf16* y = Y + row * D_;
  y[t]       = f2b(d0 * rs * G[t]       + Bet[t]);
  y[t + 256] = f2b(d1 * rs * G[t + 256] + Bet[t + 256]);
  y[t + 512] = f2b(d2 * rs * G[t + 512] + Bet[t + 512]);
}

// LN over internal bf16 buffer
__global__ __launch_bounds__(256)
void ln_h_kernel(const bf16* __restrict__ X, const float* __restrict__ G,
                 const float* __restrict__ Bet, bf16* __restrict__ Y)
{
  const int t = threadIdx.x;
  const size_t row = blockIdx.x;
  const bf16* x = X + row * D_;
  float v0 = b2f(x[t]), v1 = b2f(x[t + 256]), v2 = b2f(x[t + 512]);
  float s = v0 + v1 + v2;
#pragma unroll
  for (int d = 32; d >= 1; d >>= 1) s += __shfl_xor(s, d, 64);
  __shared__ float red[8];
  const int wv = t >> 6, ln = t & 63;
  if (ln == 0) red[wv] = s;
  __syncthreads();
  const float mu = (red[0] + red[1] + red[2] + red[3]) * (1.0f / 768.0f);
  const float d0 = v0 - mu, d1 = v1 - mu, d2 = v2 - mu;
  float sq = d0 * d0 + d1 * d1 + d2 * d2;
#pragma unroll
  for (int d = 32; d >= 1; d >>= 1) sq += __shfl_xor(sq, d, 64);
  if (ln == 0) red[4 + wv] = sq;
  __syncthreads();
  const float var = (red[4] + red[5] + red[6] + red[7]) * (1.0f / 768.0f);
  const float rs = rsqrtf(var + 1e-5f);
  bf16* y = Y + row * D_;
  y[t]       = f2b(d0 * rs * G[t]       + Bet[t]);
  y[t + 256] = f2b(d1 * rs * G[t + 256] + Bet[t + 256]);
  y[t + 512] = f2b(d2 * rs * G[t + 512] + Bet[t + 512]);
}

// ---------------- LDS-free bf16 GEMM: C[M,N] = A[M,K] @ B[K,N] (B packed) ------------
// block 256 thr = 4 waves (2x2), tile 128x128, each wave 64x64 (4x4 of 16x16x32 MFMA)
// mode 0: QKV epilogue (+bias; n<1536 -> qk buf stride 1536; n>=1536 -> packed Vp)
// mode 1: +bias, bf16 C (stride N)
// mode 2: +bias, exact-erf GELU, bf16 C (stride N)
// mode 3: +bias, FLOAT Cf (stride N)  <- final output is fp32
__global__ __launch_bounds__(256)
void gemm_kernel(const bf16* __restrict__ A, const bf16* __restrict__ Bp,
                 const float* __restrict__ bias, bf16* __restrict__ C,
                 bf16* __restrict__ Vp, float* __restrict__ Cf,
                 int K, int N, int mode)
{
  const int wave = threadIdx.x >> 6;
  const int lane = threadIdx.x & 63;
  const int l15 = lane & 15;
  const int qd  = lane >> 4;
  const size_t m0 = (size_t)blockIdx.y * 128 + (wave >> 1) * 64;
  const int n0 = blockIdx.x * 128 + (wave & 1) * 64;

  const bf16* Abase[4];
#pragma unroll
  for (int mt = 0; mt < 4; ++mt)
    Abase[mt] = A + (m0 + mt * 16 + l15) * (size_t)K + qd * 8;
  const bf16* Bbase[4];
#pragma unroll
  for (int nt = 0; nt < 4; ++nt)
    Bbase[nt] = Bp + ((size_t)qd * N + (n0 + nt * 16 + l15)) * 8;

  f32x4 acc[4][4];
#pragma unroll
  for (int i = 0; i < 4; ++i)
#pragma unroll
    for (int j = 0; j < 4; ++j) acc[i][j] = zero4();

  uint4 a[2][4], b[2][4];
#pragma unroll
  for (int mt = 0; mt < 4; ++mt) a[0][mt] = *(const uint4*)(Abase[mt]);
#pragma unroll
  for (int nt = 0; nt < 4; ++nt) b[0][nt] = *(const uint4*)(Bbase[nt]);

  int cur = 0;
  for (int k0 = 32; k0 < K; k0 += 32) {
    const int nxt = cur ^ 1;
#pragma unroll
    for (int mt = 0; mt < 4; ++mt) a[nxt][mt] = *(const uint4*)(Abase[mt] + k0);
#pragma unroll
    for (int nt = 0; nt < 4; ++nt) b[nxt][nt] = *(const uint4*)(Bbase[nt] + (size_t)(k0 >> 3) * N * 8);
#pragma unroll
    for (int mt = 0; mt < 4; ++mt)
#pragma unroll
      for (int nt = 0; nt < 4; ++nt)
        acc[mt][nt] = mfma16(a[cur][mt], b[cur][nt], acc[mt][nt]);
    cur = nxt;
  }
#pragma unroll
  for (int mt = 0; mt < 4; ++mt)
#pragma unroll
    for (int nt = 0; nt < 4; ++nt)
      acc[mt][nt] = mfma16(a[cur][mt], b[cur][nt], acc[mt][nt]);

  // epilogue: C row = (lane>>4)*4 + r, col = lane&15  [verified C/D layout]
#pragma unroll
  for (int nt = 0; nt < 4; ++nt) {
    const int col = n0 + nt * 16 + l15;
    const float bs = bias[col];
#pragma unroll
    for (int mt = 0; mt < 4; ++mt) {
#pragma unroll
      for (int r = 0; r < 4; ++r) {
        const size_t row = m0 + mt * 16 + qd * 4 + r;
        float v = acc[mt][nt][r] + bs;
        if (mode == 2) v = 0.5f * v * (1.0f + erff(v * 0.70710678118654752f));
        if (mode == 0) {
          if (col < SQK) {
            C[row * SQK + col] = f2b(v);
          } else {
            const int bb = (int)(row >> 11);
            const int ss = (int)(row & 2047);
            const int hh = (col - SQK) >> 6;
            const int ee = col & 63;
            // Vp[b][h][s/8][e][s&7]
            Vp[(((size_t)bb * H_ + hh) * 256 + (ss >> 3)) * 512 + ee * 8 + (ss & 7)] = f2b(v);
          }
        } else if (mode == 3) {
          Cf[row * (size_t)N + col] = v;
        } else {
          C[row * (size_t)N + col] = f2b(v);
        }
      }
    }
  }
}

// ---------------- flash attention: block = 128 q-rows of one (b,h), 4 waves ----------
__global__ __launch_bounds__(256)
void attn_kernel(const bf16* __restrict__ QK, const bf16* __restrict__ Vp,
                 bf16* __restrict__ O)
{
  const int wave = threadIdx.x >> 6;
  const int lane = threadIdx.x & 63;
  const int l15 = lane & 15;
  const int qd  = lane >> 4;
  const int bh = blockIdx.y;
  const int b  = bh / H_;
  const int h  = bh % H_;
  const int q0 = blockIdx.x * 128 + wave * 32;   // this wave's first q-row

  const bf16* Qb = QK + (size_t)b * S_ * SQK + h * HD_;
  const bf16* Kb = Qb + D_;                       // K block lives at col+768
  const bf16* Vb = Vp + (size_t)bh * 256 * 512;

  uint4 qf[2][2];
#pragma unroll
  for (int mt = 0; mt < 2; ++mt)
#pragma unroll
    for (int ks = 0; ks < 2; ++ks)
      qf[mt][ks] = *(const uint4*)(Qb + (size_t)(q0 + mt * 16 + l15) * SQK + ks * 32 + qd * 8);

  float m_[2][4], l_[2][4];
  f32x4 o_[2][4];
#pragma unroll
  for (int mt = 0; mt < 2; ++mt)
#pragma unroll
    for (int r = 0; r < 4; ++r) { m_[mt][r] = -INFINITY; l_[mt][r] = 0.0f; }
#pragma unroll
  for (int mt = 0; mt < 2; ++mt)
#pragma unroll
    for (int dt = 0; dt < 4; ++dt) o_[mt][dt] = zero4();

  __shared__ __align__(16) unsigned short Pl[4][32 * 88];  // per-wave 32 x 64, stride 88
  unsigned short* Pw = &Pl[wave][0];

  const float L2E = 1.44269504088896f;

  for (int sk = 0; sk < S_; sk += 64) {
    // --- S = Q K^T * 1/8 ---
    uint4 kf[2][4];
#pragma unroll
    for (int ks = 0; ks < 2; ++ks)
#pragma unroll
      for (int nt = 0; nt < 4; ++nt)
        kf[ks][nt] = *(const uint4*)(Kb + (size_t)(sk + nt * 16 + l15) * SQK + ks * 32 + qd * 8);
    f32x4 s[2][4];
#pragma unroll
    for (int mt = 0; mt < 2; ++mt)
#pragma unroll
      for (int nt = 0; nt < 4; ++nt) s[mt][nt] = zero4();
#pragma unroll
    for (int ks = 0; ks < 2; ++ks)
#pragma unroll
      for (int mt = 0; mt < 2; ++mt)
#pragma unroll
        for (int nt = 0; nt < 4; ++nt)
          s[mt][nt] = mfma16(qf[mt][ks], kf[ks][nt], s[mt][nt]);
#pragma unroll
    for (int mt = 0; mt < 2; ++mt)
#pragma unroll
      for (int nt = 0; nt < 4; ++nt)
#pragma unroll
        for (int r = 0; r < 4; ++r) s[mt][nt][r] *= 0.125f;

    // --- online softmax (row q lives on the 16-lane group sharing qd) ---
    float alpha[2][4];
#pragma unroll
    for (int mt = 0; mt < 2; ++mt) {
#pragma unroll
      for (int r = 0; r < 4; ++r) {
        float mx = fmaxf(fmaxf(s[mt][0][r], s[mt][1][r]), fmaxf(s[mt][2][r], s[mt][3][r]));
#pragma unroll
        for (int d = 1; d < 16; d <<= 1) mx = fmaxf(mx, __shfl_xor(mx, d, 64));
        const float mn = fmaxf(m_[mt][r], mx);
        const float al = exp2f((m_[mt][r] - mn) * L2E);
        float ps = 0.0f;
#pragma unroll
        for (int nt = 0; nt < 4; ++nt) {
          const float p = exp2f((s[mt][nt][r] - mn) * L2E);
          s[mt][nt][r] = p;
          ps += p;
        }
#pragma unroll
        for (int d = 1; d < 16; d <<= 1) ps += __shfl_xor(ps, d, 64);
        l_[mt][r] = l_[mt][r] * al + ps;
        m_[mt][r] = mn;
        alpha[mt][r] = al;
      }
    }

    // --- P: C-layout -> LDS -> A-layout ---
    __syncthreads();
#pragma unroll
    for (int mt = 0; mt < 2; ++mt)
#pragma unroll
      for (int nt = 0; nt < 4; ++nt)
#pragma unroll
        for (int r = 0; r < 4; ++r)
          Pw[(mt * 16 + qd * 4 + r) * 88 + nt * 16 + l15] = f2bits(s[mt][nt][r]);
    __syncthreads();
    uint4 pf[2][2];
#pragma unroll
    for (int mt = 0; mt < 2; ++mt)
#pragma unroll
      for (int ks = 0; ks < 2; ++ks)
        pf[mt][ks] = *(const uint4*)(Pw + (mt * 16 + l15) * 88 + ks * 32 + qd * 8);

    // --- rescale O, then O += P V ---
#pragma unroll
    for (int mt = 0; mt < 2; ++mt)
#pragma unroll
      for (int dt = 0; dt < 4; ++dt)
#pragma unroll
        for (int r = 0; r < 4; ++r) o_[mt][dt][r] *= alpha[mt][r];
    uint4 vf[2][4];
#pragma unroll
    for (int ks = 0; ks < 2; ++ks)
#pragma unroll
      for (int dt = 0; dt < 4; ++dt)
        vf[ks][dt] = *(const uint4*)(Vb + ((size_t)(sk >> 3) + ks * 4 + qd) * 512 + (dt * 16 + l15) * 8);
#pragma unroll
    for (int ks = 0; ks < 2; ++ks)
#pragma unroll
      for (int mt = 0; mt < 2; ++mt)
#pragma unroll
        for (int dt = 0; dt < 4; ++dt)
          o_[mt][dt] = mfma16(pf[mt][ks], vf[ks][dt], o_[mt][dt]);
  }

  // --- epilogue: O / l  -> o_buf[b, s, h*64 + e] ---
  const size_t tok0 = (size_t)b * S_ + q0;
#pragma unroll
  for (int mt = 0; mt < 2; ++mt) {
#pragma unroll
    for (int r = 0; r < 4; ++r) {
      const float inv = 1.0f / l_[mt][r];
      const size_t row = tok0 + mt * 16 + qd * 4 + r;
#pragma unroll
      for (int dt = 0; dt < 4; ++dt)
        O[row * D_ + h * HD_ + dt * 16 + l15] = f2b(o_[mt][dt][r] * inv);
    }
  }
}

// ---------------- orchestration ----------------
extern "C" void kernel_launch(void* const* d_in, const int* in_sizes, int n_in,
                              void* d_out, int out_size, void* d_ws, size_t ws_size,
                              hipStream_t stream)
{
  const float* x   = (const float*)d_in[0];
  const float* Wq  = (const float*)d_in[1];
  const float* bq  = (const float*)d_in[2];
  const float* Wk  = (const float*)d_in[3];
  const float* bk  = (const float*)d_in[4];
  const float* Wv  = (const float*)d_in[5];
  const float* bv  = (const float*)d_in[6];
  const float* Wo  = (const float*)d_in[7];
  const float* bo  = (const float*)d_in[8];
  const float* W1  = (const float*)d_in[9];
  const float* b1  = (const float*)d_in[10];
  const float* W2  = (const float*)d_in[11];
  const float* b2  = (const float*)d_in[12];
  const float* g1  = (const float*)d_in[13];
  const float* be1 = (const float*)d_in[14];
  const float* g2  = (const float*)d_in[15];
  const float* be2 = (const float*)d_in[16];

  // Workspace layout (peak ~61.5 MiB), 16B-aligned, live-range overlapped:
  char* ws = (char*)d_ws;
  bf16* qk     = (bf16*)(ws + 0);           // [0, 25165824)        QKV gemm -> attn
  bf16* vp     = (bf16*)(ws + 25165824);    // [25165824, 37748736) QKV gemm -> attn
  bf16* h1     = (bf16*)(ws + 37748736);    // [37748736, 50331648) LN1 -> QKV gemm
  bf16* obuf   = (bf16*)(ws + 37748736);    // reuse h1             attn -> O-proj
  bf16* abuf   = (bf16*)(ws + 0);           // reuse qk             O-proj -> LN2
  bf16* h2     = (bf16*)(ws + 25165824);    // reuse vp             LN2 -> FFN1
  bf16* fbuf   = (bf16*)(ws + 0);           // [0, 25165824)        FFN1 half -> FFN2 half
  bf16* wqkv_p = (bf16*)(ws + 50331648);    // 3,538,944
  bf16* wo_p   = (bf16*)(ws + 53870592);    // 1,179,648
  bf16* w1_p   = (bf16*)(ws + 55050240);    // 4,718,592
  bf16* w2_p   = (bf16*)(ws + 59768832);    // 4,718,592 -> 64487424
  float* bqkvf = (float*)(ws + 64487424);   // 2304 fp32 -> 64496640

  repack_qkv  <<<dim3(864),  dim3(256), 0, stream>>>(Wq, Wk, Wv, wqkv_p);
  repack_plain<<<dim3(288),  dim3(256), 0, stream>>>(Wo, wo_p, 768, 768);
  repack_plain<<<dim3(1152), dim3(256), 0, stream>>>(W1, w1_p, 768, 3072);
  repack_plain<<<dim3(1152), dim3(256), 0, stream>>>(W2, w2_p, 3072, 768);
  bias_qkv    <<<dim3(9),    dim3(256), 0, stream>>>(bq, bk, bv, bqkvf);

  ln_x_kernel<<<dim3(BS_), dim3(256), 0, stream>>>(x, g1, be1, h1);
  gemm_kernel<<<dim3(18, 64), dim3(256), 0, stream>>>(h1, wqkv_p, bqkvf, qk, vp, nullptr, 768, 2304, 0);
  attn_kernel<<<dim3(16, 48), dim3(256), 0, stream>>>(qk, vp, obuf);
  gemm_kernel<<<dim3(6, 64),  dim3(256), 0, stream>>>(obuf, wo_p, bo, abuf, nullptr, nullptr, 768, 768, 1);
  ln_h_kernel<<<dim3(BS_), dim3(256), 0, stream>>>(abuf, g2, be2, h2);

  // FFN split into two M-halves so fbuf is only 24 MB; final store is FP32
  float* outp = (float*)d_out;
  gemm_kernel<<<dim3(24, 32), dim3(256), 0, stream>>>(h2, w1_p, b1, fbuf, nullptr, nullptr, 768, 3072, 2);
  gemm_kernel<<<dim3(6, 32),  dim3(256), 0, stream>>>(fbuf, w2_p, b2, nullptr, nullptr, outp, 3072, 768, 3);
  gemm_kernel<<<dim3(24, 32), dim3(256), 0, stream>>>(h2 + (size_t)4096 * D_, w1_p, b1, fbuf, nullptr, nullptr, 768, 3072, 2);
  gemm_kernel<<<dim3(6, 32),  dim3(256), 0, stream>>>(fbuf, w2_p, b2, nullptr, nullptr, outp + (size_t)4096 * D_, 3072, 768, 3);
}

// Round 5
// 639.790 us; speedup vs baseline: 2.4649x; 2.4649x over previous
//
#include <hip/hip_runtime.h>
#include <hip/hip_bf16.h>
#include <math.h>

typedef __hip_bfloat16 bf16;
typedef __attribute__((ext_vector_type(8))) short short8;
typedef __attribute__((ext_vector_type(4))) float f32x4;

#define D_  768
#define H_  12
#define HD_ 64
#define F_  3072
#define B_  4
#define S_  2048
#define BS_ (B_*S_)
#define SQK 1536   // Q,K buffer row stride (V lives in packed Vp)

__device__ __forceinline__ float b2f(bf16 x){ return __bfloat162float(x); }
__device__ __forceinline__ bf16  f2b(float x){ return __float2bfloat16(x); }

union BU { bf16 b; unsigned short u; };
__device__ __forceinline__ unsigned short f2bits(float x){ BU t; t.b = __float2bfloat16(x); return t.u; }

__device__ __forceinline__ f32x4 zero4(){ f32x4 z; z.x=0.f; z.y=0.f; z.z=0.f; z.w=0.f; return z; }

__device__ __forceinline__ f32x4 mfma16(uint4 a, uint4 b, f32x4 c){
  union U { uint4 u; short8 s; };
  U A, B; A.u = a; B.u = b;
  return __builtin_amdgcn_mfma_f32_16x16x32_bf16(A.s, B.s, c, 0, 0, 0);
}

// async global->LDS, 16 B per lane (global_load_lds_dwordx4)
typedef const __attribute__((address_space(1))) void gvoid;
typedef __attribute__((address_space(3))) void lvoid;
__device__ __forceinline__ void load_lds16(const void* g, void* l){
  __builtin_amdgcn_global_load_lds((gvoid*)g, (lvoid*)l, 16, 0, 0);
}

// ---------------- weight repack (fp32 -> bf16 W^T): Wt[n][k] = W[k][n] -------------
// one thread per 16B output pack (n, kg): reads 8 floats down column n.
__global__ __launch_bounds__(256)
void repack_t(const float* __restrict__ W, bf16* __restrict__ Wt, int K, int N)
{
  const int t = blockIdx.x * 256 + threadIdx.x;   // exact grids
  const int n = t % N;
  const int kg = t / N;
  const float* src = W + (size_t)kg * 8 * N + n;
  union { unsigned short u16[8]; uint4 u; } pk;
#pragma unroll
  for (int j = 0; j < 8; ++j) pk.u16[j] = f2bits(src[(size_t)j * N]);
  *(uint4*)(Wt + ((size_t)n * (K >> 3) + kg) * 8) = pk.u;
}

// QKV combined W^T: rows n in [0,2304): sel=n/768, h=(n%768)>>6, e=n&63; K=768
__global__ __launch_bounds__(256)
void repack_qkv_t(const float* __restrict__ Wq, const float* __restrict__ Wk,
                  const float* __restrict__ Wv, bf16* __restrict__ Wt)
{
  const int t = blockIdx.x * 256 + threadIdx.x;   // 864*256 = 96*2304 exact
  const int n = t % 2304;
  const int kg = t / 2304;                        // 0..95
  const int sel = n / 768;
  const int nn = n - sel * 768;
  const int hh = nn >> 6;
  const int ee = nn & 63;
  const float* W = (sel == 0) ? Wq : (sel == 1) ? Wk : Wv;
  const float* src = W + ((size_t)hh * 768 + (size_t)kg * 8) * 64 + ee;
  union { unsigned short u16[8]; uint4 u; } pk;
#pragma unroll
  for (int j = 0; j < 8; ++j) pk.u16[j] = f2bits(src[(size_t)j * 64]);
  *(uint4*)(Wt + ((size_t)n * 96 + kg) * 8) = pk.u;
}

__global__ __launch_bounds__(256)
void bias_qkv(const float* __restrict__ bq, const float* __restrict__ bk,
              const float* __restrict__ bv, float* __restrict__ out)
{
  const int t = blockIdx.x * 256 + threadIdx.x;   // 9*256 = 2304 exact
  out[t] = (t < 768) ? bq[t] : (t < 1536) ? bk[t - 768] : bv[t - 1536];
}

// ---------------- LayerNorm: one block per token, 256 thr, D=768=256*3 ----------------
__global__ __launch_bounds__(256)
void ln_x_kernel(const float* __restrict__ X, const float* __restrict__ G,
                 const float* __restrict__ Bet, bf16* __restrict__ Y)
{
  const int t = threadIdx.x;
  const size_t row = blockIdx.x;
  const float* x = X + row * D_;
  float v0 = x[t], v1 = x[t + 256], v2 = x[t + 512];
  float s = v0 + v1 + v2;
#pragma unroll
  for (int d = 32; d >= 1; d >>= 1) s += __shfl_xor(s, d, 64);
  __shared__ float red[8];
  const int wv = t >> 6, ln = t & 63;
  if (ln == 0) red[wv] = s;
  __syncthreads();
  const float mu = (red[0] + red[1] + red[2] + red[3]) * (1.0f / 768.0f);
  const float d0 = v0 - mu, d1 = v1 - mu, d2 = v2 - mu;
  float sq = d0 * d0 + d1 * d1 + d2 * d2;
#pragma unroll
  for (int d = 32; d >= 1; d >>= 1) sq += __shfl_xor(sq, d, 64);
  if (ln == 0) red[4 + wv] = sq;
  __syncthreads();
  const float var = (red[4] + red[5] + red[6] + red[7]) * (1.0f / 768.0f);
  const float rs = rsqrtf(var + 1e-5f);
  bf16* y = Y + row * D_;
  y[t]       = f2b(d0 * rs * G[t]       + Bet[t]);
  y[t + 256] = f2b(d1 * rs * G[t + 256] + Bet[t + 256]);
  y[t + 512] = f2b(d2 * rs * G[t + 512] + Bet[t + 512]);
}

__global__ __launch_bounds__(256)
void ln_h_kernel(const bf16* __restrict__ X, const float* __restrict__ G,
                 const float* __restrict__ Bet, bf16* __restrict__ Y)
{
  const int t = threadIdx.x;
  const size_t row = blockIdx.x;
  const bf16* x = X + row * D_;
  float v0 = b2f(x[t]), v1 = b2f(x[t + 256]), v2 = b2f(x[t + 512]);
  float s = v0 + v1 + v2;
#pragma unroll
  for (int d = 32; d >= 1; d >>= 1) s += __shfl_xor(s, d, 64);
  __shared__ float red[8];
  const int wv = t >> 6, ln = t & 63;
  if (ln == 0) red[wv] = s;
  __syncthreads();
  const float mu = (red[0] + red[1] + red[2] + red[3]) * (1.0f / 768.0f);
  const float d0 = v0 - mu, d1 = v1 - mu, d2 = v2 - mu;
  float sq = d0 * d0 + d1 * d1 + d2 * d2;
#pragma unroll
  for (int d = 32; d >= 1; d >>= 1) sq += __shfl_xor(sq, d, 64);
  if (ln == 0) red[4 + wv] = sq;
  __syncthreads();
  const float var = (red[4] + red[5] + red[6] + red[7]) * (1.0f / 768.0f);
  const float rs = rsqrtf(var + 1e-5f);
  bf16* y = Y + row * D_;
  y[t]       = f2b(d0 * rs * G[t]       + Bet[t]);
  y[t + 256] = f2b(d1 * rs * G[t + 256] + Bet[t + 256]);
  y[t + 512] = f2b(d2 * rs * G[t + 512] + Bet[t + 512]);
}

// ------------- m97-style LDS-staged GEMM: C[M,N] = A[M,K] x Wt[N,K]^T --------------
// block 256 = 4 waves (2x2), tile 128x128, BK=32, global_load_lds width 16,
// 8 ds_read_b128 + 16 MFMA per wave per K-step, 2 barriers per K-step.
// modes: 0 QKV epilogue (qk/Vp), 1 bf16 C, 2 GELU bf16 C, 3 fp32 Cf
__global__ __launch_bounds__(256)
void gemm_lds(const bf16* __restrict__ A, const bf16* __restrict__ Wt,
              const float* __restrict__ bias, bf16* __restrict__ C,
              bf16* __restrict__ Vp, float* __restrict__ Cf,
              int K, int N, int mode)
{
  __shared__ __align__(16) bf16 As[128 * 32];   // [row][k], 64 B rows
  __shared__ __align__(16) bf16 Bs[128 * 32];

  const int tid = threadIdx.x;
  const int wave = tid >> 6, lane = tid & 63;
  const int l15 = lane & 15, qd = lane >> 4;
  const int wy = wave >> 1, wx = wave & 1;
  const size_t m0 = (size_t)blockIdx.y * 128;
  const int n0 = blockIdx.x * 128;

  // staging: 512 packs of 16 B per tile; thread does packs tid and tid+256
  const int r0 = tid >> 2, c0 = tid & 3;        // row 0..63, kchunk 0..3
  const bf16* Ag0 = A  + (m0 + r0) * (size_t)K + c0 * 8;
  const bf16* Ag1 = A  + (m0 + r0 + 64) * (size_t)K + c0 * 8;
  const bf16* Bg0 = Wt + (size_t)(n0 + r0) * K + c0 * 8;
  const bf16* Bg1 = Wt + (size_t)(n0 + r0 + 64) * K + c0 * 8;
  bf16* Al0 = As + (size_t)tid * 8;
  bf16* Al1 = As + (size_t)(tid + 256) * 8;
  bf16* Bl0 = Bs + (size_t)tid * 8;
  bf16* Bl1 = Bs + (size_t)(tid + 256) * 8;

  f32x4 acc[4][4];
#pragma unroll
  for (int i = 0; i < 4; ++i)
#pragma unroll
    for (int j = 0; j < 4; ++j) acc[i][j] = zero4();

  const int arow = wy * 64;   // wave's A-row base in tile
  const int brow = wx * 64;   // wave's B-row base in tile

  for (int k0 = 0; k0 < K; k0 += 32) {
    load_lds16(Ag0 + k0, Al0);
    load_lds16(Ag1 + k0, Al1);
    load_lds16(Bg0 + k0, Bl0);
    load_lds16(Bg1 + k0, Bl1);
    __syncthreads();            // compiler emits vmcnt(0) drain before barrier
    uint4 af[4], bfr[4];
#pragma unroll
    for (int mt = 0; mt < 4; ++mt)
      af[mt] = *(const uint4*)(As + (size_t)(arow + mt * 16 + l15) * 32 + qd * 8);
#pragma unroll
    for (int nt = 0; nt < 4; ++nt)
      bfr[nt] = *(const uint4*)(Bs + (size_t)(brow + nt * 16 + l15) * 32 + qd * 8);
#pragma unroll
    for (int mt = 0; mt < 4; ++mt)
#pragma unroll
      for (int nt = 0; nt < 4; ++nt)
        acc[mt][nt] = mfma16(af[mt], bfr[nt], acc[mt][nt]);
    __syncthreads();
  }

  // epilogue: C row = (lane>>4)*4 + r, col = lane&15  [verified C/D layout]
  const size_t wm0 = m0 + arow;
  const int wn0 = n0 + brow;
#pragma unroll
  for (int nt = 0; nt < 4; ++nt) {
    const int col = wn0 + nt * 16 + l15;
    const float bs = bias[col];
#pragma unroll
    for (int mt = 0; mt < 4; ++mt) {
#pragma unroll
      for (int r = 0; r < 4; ++r) {
        const size_t row = wm0 + mt * 16 + qd * 4 + r;
        float v = acc[mt][nt][r] + bs;
        if (mode == 2) v = 0.5f * v * (1.0f + erff(v * 0.70710678118654752f));
        if (mode == 0) {
          if (col < SQK) {
            C[row * SQK + col] = f2b(v);
          } else {
            const int bb = (int)(row >> 11);
            const int ss = (int)(row & 2047);
            const int hh = (col - SQK) >> 6;
            const int ee = col & 63;
            // Vp[b][h][s/8][e][s&7]
            Vp[(((size_t)bb * H_ + hh) * 256 + (ss >> 3)) * 512 + ee * 8 + (ss & 7)] = f2b(v);
          }
        } else if (mode == 3) {
          Cf[row * (size_t)N + col] = v;
        } else {
          C[row * (size_t)N + col] = f2b(v);
        }
      }
    }
  }
}

// ---------------- flash attention: block = 128 q-rows of one (b,h), 4 waves ----------
__global__ __launch_bounds__(256)
void attn_kernel(const bf16* __restrict__ QK, const bf16* __restrict__ Vp,
                 bf16* __restrict__ O)
{
  const int wave = threadIdx.x >> 6;
  const int lane = threadIdx.x & 63;
  const int l15 = lane & 15;
  const int qd  = lane >> 4;
  const int bh = blockIdx.y;
  const int b  = bh / H_;
  const int h  = bh % H_;
  const int q0 = blockIdx.x * 128 + wave * 32;   // this wave's first q-row

  const bf16* Qb = QK + (size_t)b * S_ * SQK + h * HD_;
  const bf16* Kb = Qb + D_;                       // K block lives at col+768
  const bf16* Vb = Vp + (size_t)bh * 256 * 512;

  uint4 qf[2][2];
#pragma unroll
  for (int mt = 0; mt < 2; ++mt)
#pragma unroll
    for (int ks = 0; ks < 2; ++ks)
      qf[mt][ks] = *(const uint4*)(Qb + (size_t)(q0 + mt * 16 + l15) * SQK + ks * 32 + qd * 8);

  float m_[2][4], l_[2][4];
  f32x4 o_[2][4];
#pragma unroll
  for (int mt = 0; mt < 2; ++mt)
#pragma unroll
    for (int r = 0; r < 4; ++r) { m_[mt][r] = -INFINITY; l_[mt][r] = 0.0f; }
#pragma unroll
  for (int mt = 0; mt < 2; ++mt)
#pragma unroll
    for (int dt = 0; dt < 4; ++dt) o_[mt][dt] = zero4();

  __shared__ __align__(16) unsigned short Pl[4][32 * 88];  // per-wave 32 x 64, stride 88
  unsigned short* Pw = &Pl[wave][0];

  const float L2E = 1.44269504088896f;

  for (int sk = 0; sk < S_; sk += 64) {
    // --- S = Q K^T * 1/8 ---
    uint4 kf[2][4];
#pragma unroll
    for (int ks = 0; ks < 2; ++ks)
#pragma unroll
      for (int nt = 0; nt < 4; ++nt)
        kf[ks][nt] = *(const uint4*)(Kb + (size_t)(sk + nt * 16 + l15) * SQK + ks * 32 + qd * 8);
    f32x4 s[2][4];
#pragma unroll
    for (int mt = 0; mt < 2; ++mt)
#pragma unroll
      for (int nt = 0; nt < 4; ++nt) s[mt][nt] = zero4();
#pragma unroll
    for (int ks = 0; ks < 2; ++ks)
#pragma unroll
      for (int mt = 0; mt < 2; ++mt)
#pragma unroll
        for (int nt = 0; nt < 4; ++nt)
          s[mt][nt] = mfma16(qf[mt][ks], kf[ks][nt], s[mt][nt]);
#pragma unroll
    for (int mt = 0; mt < 2; ++mt)
#pragma unroll
      for (int nt = 0; nt < 4; ++nt)
#pragma unroll
        for (int r = 0; r < 4; ++r) s[mt][nt][r] *= 0.125f;

    // --- online softmax (row q lives on the 16-lane group sharing qd) ---
    float alpha[2][4];
#pragma unroll
    for (int mt = 0; mt < 2; ++mt) {
#pragma unroll
      for (int r = 0; r < 4; ++r) {
        float mx = fmaxf(fmaxf(s[mt][0][r], s[mt][1][r]), fmaxf(s[mt][2][r], s[mt][3][r]));
#pragma unroll
        for (int d = 1; d < 16; d <<= 1) mx = fmaxf(mx, __shfl_xor(mx, d, 64));
        const float mn = fmaxf(m_[mt][r], mx);
        const float al = exp2f((m_[mt][r] - mn) * L2E);
        float ps = 0.0f;
#pragma unroll
        for (int nt = 0; nt < 4; ++nt) {
          const float p = exp2f((s[mt][nt][r] - mn) * L2E);
          s[mt][nt][r] = p;
          ps += p;
        }
#pragma unroll
        for (int d = 1; d < 16; d <<= 1) ps += __shfl_xor(ps, d, 64);
        l_[mt][r] = l_[mt][r] * al + ps;
        m_[mt][r] = mn;
        alpha[mt][r] = al;
      }
    }

    // --- P: C-layout -> LDS -> A-layout ---
    __syncthreads();
#pragma unroll
    for (int mt = 0; mt < 2; ++mt)
#pragma unroll
      for (int nt = 0; nt < 4; ++nt)
#pragma unroll
        for (int r = 0; r < 4; ++r)
          Pw[(mt * 16 + qd * 4 + r) * 88 + nt * 16 + l15] = f2bits(s[mt][nt][r]);
    __syncthreads();
    uint4 pf[2][2];
#pragma unroll
    for (int mt = 0; mt < 2; ++mt)
#pragma unroll
      for (int ks = 0; ks < 2; ++ks)
        pf[mt][ks] = *(const uint4*)(Pw + (mt * 16 + l15) * 88 + ks * 32 + qd * 8);

    // --- rescale O, then O += P V ---
#pragma unroll
    for (int mt = 0; mt < 2; ++mt)
#pragma unroll
      for (int dt = 0; dt < 4; ++dt)
#pragma unroll
        for (int r = 0; r < 4; ++r) o_[mt][dt][r] *= alpha[mt][r];
    uint4 vf[2][4];
#pragma unroll
    for (int ks = 0; ks < 2; ++ks)
#pragma unroll
      for (int dt = 0; dt < 4; ++dt)
        vf[ks][dt] = *(const uint4*)(Vb + ((size_t)(sk >> 3) + ks * 4 + qd) * 512 + (dt * 16 + l15) * 8);
#pragma unroll
    for (int ks = 0; ks < 2; ++ks)
#pragma unroll
      for (int mt = 0; mt < 2; ++mt)
#pragma unroll
        for (int dt = 0; dt < 4; ++dt)
          o_[mt][dt] = mfma16(pf[mt][ks], vf[ks][dt], o_[mt][dt]);
  }

  // --- epilogue: O / l  -> o_buf[b, s, h*64 + e] ---
  const size_t tok0 = (size_t)b * S_ + q0;
#pragma unroll
  for (int mt = 0; mt < 2; ++mt) {
#pragma unroll
    for (int r = 0; r < 4; ++r) {
      const float inv = 1.0f / l_[mt][r];
      const size_t row = tok0 + mt * 16 + qd * 4 + r;
#pragma unroll
      for (int dt = 0; dt < 4; ++dt)
        O[row * D_ + h * HD_ + dt * 16 + l15] = f2b(o_[mt][dt][r] * inv);
    }
  }
}

// ---------------- orchestration ----------------
extern "C" void kernel_launch(void* const* d_in, const int* in_sizes, int n_in,
                              void* d_out, int out_size, void* d_ws, size_t ws_size,
                              hipStream_t stream)
{
  const float* x   = (const float*)d_in[0];
  const float* Wq  = (const float*)d_in[1];
  const float* bq  = (const float*)d_in[2];
  const float* Wk  = (const float*)d_in[3];
  const float* bk  = (const float*)d_in[4];
  const float* Wv  = (const float*)d_in[5];
  const float* bv  = (const float*)d_in[6];
  const float* Wo  = (const float*)d_in[7];
  const float* bo  = (const float*)d_in[8];
  const float* W1  = (const float*)d_in[9];
  const float* b1  = (const float*)d_in[10];
  const float* W2  = (const float*)d_in[11];
  const float* b2  = (const float*)d_in[12];
  const float* g1  = (const float*)d_in[13];
  const float* be1 = (const float*)d_in[14];
  const float* g2  = (const float*)d_in[15];
  const float* be2 = (const float*)d_in[16];

  // full-M FFN needs 77,079,552 B of workspace; otherwise split (64,496,640 B)
  const bool full = ws_size >= (size_t)77079552;

  char* ws = (char*)d_ws;
  bf16* qk     = (bf16*)(ws + 0);           // QKV gemm -> attn
  bf16* vp     = (bf16*)(ws + 25165824);    // QKV gemm -> attn
  bf16* h1     = (bf16*)(ws + 37748736);    // LN1 -> QKV gemm
  bf16* obuf   = h1;                        // attn -> O-proj (h1 dead)
  bf16* abuf   = (bf16*)(ws + 0);           // O-proj -> LN2 (qk dead)
  bf16* h2     = (bf16*)(ws + (full ? 50331648u : 25165824u));  // LN2 -> FFN1
  bf16* fbuf   = (bf16*)(ws + 0);           // FFN1 -> FFN2 (full: 48 MB; split: 24 MB)
  const size_t wb = full ? 62914560u : 50331648u;
  bf16* wqkv_p = (bf16*)(ws + wb);                    // 3,538,944 B
  bf16* wo_p   = (bf16*)(ws + wb + 3538944u);         // 1,179,648 B
  bf16* w1_p   = (bf16*)(ws + wb + 4718592u);         // 4,718,592 B
  bf16* w2_p   = (bf16*)(ws + wb + 9437184u);         // 4,718,592 B
  float* bqkvf = (float*)(ws + wb + 14155776u);       // 9,216 B

  repack_qkv_t<<<dim3(864),  dim3(256), 0, stream>>>(Wq, Wk, Wv, wqkv_p);
  repack_t    <<<dim3(288),  dim3(256), 0, stream>>>(Wo, wo_p, 768, 768);
  repack_t    <<<dim3(1152), dim3(256), 0, stream>>>(W1, w1_p, 768, 3072);
  repack_t    <<<dim3(1152), dim3(256), 0, stream>>>(W2, w2_p, 3072, 768);
  bias_qkv    <<<dim3(9),    dim3(256), 0, stream>>>(bq, bk, bv, bqkvf);

  ln_x_kernel<<<dim3(BS_), dim3(256), 0, stream>>>(x, g1, be1, h1);
  gemm_lds<<<dim3(18, 64), dim3(256), 0, stream>>>(h1, wqkv_p, bqkvf, qk, vp, nullptr, 768, 2304, 0);
  attn_kernel<<<dim3(16, 48), dim3(256), 0, stream>>>(qk, vp, obuf);
  gemm_lds<<<dim3(6, 64),  dim3(256), 0, stream>>>(obuf, wo_p, bo, abuf, nullptr, nullptr, 768, 768, 1);
  ln_h_kernel<<<dim3(BS_), dim3(256), 0, stream>>>(abuf, g2, be2, h2);

  float* outp = (float*)d_out;
  if (full) {
    gemm_lds<<<dim3(24, 64), dim3(256), 0, stream>>>(h2, w1_p, b1, fbuf, nullptr, nullptr, 768, 3072, 2);
    gemm_lds<<<dim3(6, 64),  dim3(256), 0, stream>>>(fbuf, w2_p, b2, nullptr, nullptr, outp, 3072, 768, 3);
  } else {
    gemm_lds<<<dim3(24, 32), dim3(256), 0, stream>>>(h2, w1_p, b1, fbuf, nullptr, nullptr, 768, 3072, 2);
    gemm_lds<<<dim3(6, 32),  dim3(256), 0, stream>>>(fbuf, w2_p, b2, nullptr, nullptr, outp, 3072, 768, 3);
    gemm_lds<<<dim3(24, 32), dim3(256), 0, stream>>>(h2 + (size_t)4096 * D_, w1_p, b1, fbuf, nullptr, nullptr, 768, 3072, 2);
    gemm_lds<<<dim3(6, 32),  dim3(256), 0, stream>>>(fbuf, w2_p, b2, nullptr, nullptr, outp + (size_t)4096 * D_, 3072, 768, 3);
  }
}

// Round 6
// 526.606 us; speedup vs baseline: 2.9947x; 1.2149x over previous
//
#include <hip/hip_runtime.h>
#include <hip/hip_bf16.h>
#include <math.h>

typedef __hip_bfloat16 bf16;
typedef __attribute__((ext_vector_type(8))) short short8;
typedef __attribute__((ext_vector_type(4))) float f32x4;

#define D_  768
#define H_  12
#define HD_ 64
#define F_  3072
#define B_  4
#define S_  2048
#define BS_ (B_*S_)
#define SQK 1536   // Q,K buffer row stride (V lives in packed Vp)

__device__ __forceinline__ float b2f(bf16 x){ return __bfloat162float(x); }
__device__ __forceinline__ bf16  f2b(float x){ return __float2bfloat16(x); }

union BU { bf16 b; unsigned short u; };
__device__ __forceinline__ unsigned short f2bits(float x){ BU t; t.b = __float2bfloat16(x); return t.u; }

__device__ __forceinline__ f32x4 zero4(){ f32x4 z; z.x=0.f; z.y=0.f; z.z=0.f; z.w=0.f; return z; }

__device__ __forceinline__ f32x4 mfma16(uint4 a, uint4 b, f32x4 c){
  union U { uint4 u; short8 s; };
  U A, B; A.u = a; B.u = b;
  return __builtin_amdgcn_mfma_f32_16x16x32_bf16(A.s, B.s, c, 0, 0, 0);
}

// async global->LDS, 16 B per lane (global_load_lds_dwordx4)
typedef const __attribute__((address_space(1))) void gvoid;
typedef __attribute__((address_space(3))) void lvoid;
__device__ __forceinline__ void load_lds16(const void* g, void* l){
  __builtin_amdgcn_global_load_lds((gvoid*)g, (lvoid*)l, 16, 0, 0);
}

// ---------------- weight repack (fp32 -> bf16 W^T): Wt[n][k] = W[k][n] -------------
__global__ __launch_bounds__(256)
void repack_t(const float* __restrict__ W, bf16* __restrict__ Wt, int K, int N)
{
  const int t = blockIdx.x * 256 + threadIdx.x;   // exact grids
  const int n = t % N;
  const int kg = t / N;
  const float* src = W + (size_t)kg * 8 * N + n;
  union { unsigned short u16[8]; uint4 u; } pk;
#pragma unroll
  for (int j = 0; j < 8; ++j) pk.u16[j] = f2bits(src[(size_t)j * N]);
  *(uint4*)(Wt + ((size_t)n * (K >> 3) + kg) * 8) = pk.u;
}

// QKV combined W^T: rows n in [0,2304): sel=n/768, h=(n%768)>>6, e=n&63; K=768
__global__ __launch_bounds__(256)
void repack_qkv_t(const float* __restrict__ Wq, const float* __restrict__ Wk,
                  const float* __restrict__ Wv, bf16* __restrict__ Wt)
{
  const int t = blockIdx.x * 256 + threadIdx.x;   // 864*256 = 96*2304 exact
  const int n = t % 2304;
  const int kg = t / 2304;                        // 0..95
  const int sel = n / 768;
  const int nn = n - sel * 768;
  const int hh = nn >> 6;
  const int ee = nn & 63;
  const float* W = (sel == 0) ? Wq : (sel == 1) ? Wk : Wv;
  const float* src = W + ((size_t)hh * 768 + (size_t)kg * 8) * 64 + ee;
  union { unsigned short u16[8]; uint4 u; } pk;
#pragma unroll
  for (int j = 0; j < 8; ++j) pk.u16[j] = f2bits(src[(size_t)j * 64]);
  *(uint4*)(Wt + ((size_t)n * 96 + kg) * 8) = pk.u;
}

__global__ __launch_bounds__(256)
void bias_qkv(const float* __restrict__ bq, const float* __restrict__ bk,
              const float* __restrict__ bv, float* __restrict__ out)
{
  const int t = blockIdx.x * 256 + threadIdx.x;   // 9*256 = 2304 exact
  out[t] = (t < 768) ? bq[t] : (t < 1536) ? bk[t - 768] : bv[t - 1536];
}

// ---------------- LayerNorm: one block per token, 256 thr, D=768=256*3 ----------------
__global__ __launch_bounds__(256)
void ln_x_kernel(const float* __restrict__ X, const float* __restrict__ G,
                 const float* __restrict__ Bet, bf16* __restrict__ Y)
{
  const int t = threadIdx.x;
  const size_t row = blockIdx.x;
  const float* x = X + row * D_;
  float v0 = x[t], v1 = x[t + 256], v2 = x[t + 512];
  float s = v0 + v1 + v2;
#pragma unroll
  for (int d = 32; d >= 1; d >>= 1) s += __shfl_xor(s, d, 64);
  __shared__ float red[8];
  const int wv = t >> 6, ln = t & 63;
  if (ln == 0) red[wv] = s;
  __syncthreads();
  const float mu = (red[0] + red[1] + red[2] + red[3]) * (1.0f / 768.0f);
  const float d0 = v0 - mu, d1 = v1 - mu, d2 = v2 - mu;
  float sq = d0 * d0 + d1 * d1 + d2 * d2;
#pragma unroll
  for (int d = 32; d >= 1; d >>= 1) sq += __shfl_xor(sq, d, 64);
  if (ln == 0) red[4 + wv] = sq;
  __syncthreads();
  const float var = (red[4] + red[5] + red[6] + red[7]) * (1.0f / 768.0f);
  const float rs = rsqrtf(var + 1e-5f);
  bf16* y = Y + row * D_;
  y[t]       = f2b(d0 * rs * G[t]       + Bet[t]);
  y[t + 256] = f2b(d1 * rs * G[t + 256] + Bet[t + 256]);
  y[t + 512] = f2b(d2 * rs * G[t + 512] + Bet[t + 512]);
}

__global__ __launch_bounds__(256)
void ln_h_kernel(const bf16* __restrict__ X, const float* __restrict__ G,
                 const float* __restrict__ Bet, bf16* __restrict__ Y)
{
  const int t = threadIdx.x;
  const size_t row = blockIdx.x;
  const bf16* x = X + row * D_;
  float v0 = b2f(x[t]), v1 = b2f(x[t + 256]), v2 = b2f(x[t + 512]);
  float s = v0 + v1 + v2;
#pragma unroll
  for (int d = 32; d >= 1; d >>= 1) s += __shfl_xor(s, d, 64);
  __shared__ float red[8];
  const int wv = t >> 6, ln = t & 63;
  if (ln == 0) red[wv] = s;
  __syncthreads();
  const float mu = (red[0] + red[1] + red[2] + red[3]) * (1.0f / 768.0f);
  const float d0 = v0 - mu, d1 = v1 - mu, d2 = v2 - mu;
  float sq = d0 * d0 + d1 * d1 + d2 * d2;
#pragma unroll
  for (int d = 32; d >= 1; d >>= 1) sq += __shfl_xor(sq, d, 64);
  if (ln == 0) red[4 + wv] = sq;
  __syncthreads();
  const float var = (red[4] + red[5] + red[6] + red[7]) * (1.0f / 768.0f);
  const float rs = rsqrtf(var + 1e-5f);
  bf16* y = Y + row * D_;
  y[t]       = f2b(d0 * rs * G[t]       + Bet[t]);
  y[t + 256] = f2b(d1 * rs * G[t + 256] + Bet[t + 256]);
  y[t + 512] = f2b(d2 * rs * G[t + 512] + Bet[t + 512]);
}

// ------------- m97-style LDS-staged GEMM: C[M,N] = A[M,K] x Wt[N,K]^T --------------
__global__ __launch_bounds__(256)
void gemm_lds(const bf16* __restrict__ A, const bf16* __restrict__ Wt,
              const float* __restrict__ bias, bf16* __restrict__ C,
              bf16* __restrict__ Vp, float* __restrict__ Cf,
              int K, int N, int mode)
{
  __shared__ __align__(16) bf16 As[128 * 32];   // [row][k], 64 B rows
  __shared__ __align__(16) bf16 Bs[128 * 32];

  const int tid = threadIdx.x;
  const int wave = tid >> 6, lane = tid & 63;
  const int l15 = lane & 15, qd = lane >> 4;
  const int wy = wave >> 1, wx = wave & 1;
  const size_t m0 = (size_t)blockIdx.y * 128;
  const int n0 = blockIdx.x * 128;

  const int r0 = tid >> 2, c0 = tid & 3;        // row 0..63, kchunk 0..3
  const bf16* Ag0 = A  + (m0 + r0) * (size_t)K + c0 * 8;
  const bf16* Ag1 = A  + (m0 + r0 + 64) * (size_t)K + c0 * 8;
  const bf16* Bg0 = Wt + (size_t)(n0 + r0) * K + c0 * 8;
  const bf16* Bg1 = Wt + (size_t)(n0 + r0 + 64) * K + c0 * 8;
  bf16* Al0 = As + (size_t)tid * 8;
  bf16* Al1 = As + (size_t)(tid + 256) * 8;
  bf16* Bl0 = Bs + (size_t)tid * 8;
  bf16* Bl1 = Bs + (size_t)(tid + 256) * 8;

  f32x4 acc[4][4];
#pragma unroll
  for (int i = 0; i < 4; ++i)
#pragma unroll
    for (int j = 0; j < 4; ++j) acc[i][j] = zero4();

  const int arow = wy * 64;
  const int brow = wx * 64;

  for (int k0 = 0; k0 < K; k0 += 32) {
    load_lds16(Ag0 + k0, Al0);
    load_lds16(Ag1 + k0, Al1);
    load_lds16(Bg0 + k0, Bl0);
    load_lds16(Bg1 + k0, Bl1);
    __syncthreads();
    uint4 af[4], bfr[4];
#pragma unroll
    for (int mt = 0; mt < 4; ++mt)
      af[mt] = *(const uint4*)(As + (size_t)(arow + mt * 16 + l15) * 32 + qd * 8);
#pragma unroll
    for (int nt = 0; nt < 4; ++nt)
      bfr[nt] = *(const uint4*)(Bs + (size_t)(brow + nt * 16 + l15) * 32 + qd * 8);
#pragma unroll
    for (int mt = 0; mt < 4; ++mt)
#pragma unroll
      for (int nt = 0; nt < 4; ++nt)
        acc[mt][nt] = mfma16(af[mt], bfr[nt], acc[mt][nt]);
    __syncthreads();
  }

  // epilogue: C row = (lane>>4)*4 + r, col = lane&15  [verified C/D layout]
  const size_t wm0 = m0 + arow;
  const int wn0 = n0 + brow;
#pragma unroll
  for (int nt = 0; nt < 4; ++nt) {
    const int col = wn0 + nt * 16 + l15;
    const float bs = bias[col];
#pragma unroll
    for (int mt = 0; mt < 4; ++mt) {
#pragma unroll
      for (int r = 0; r < 4; ++r) {
        const size_t row = wm0 + mt * 16 + qd * 4 + r;
        float v = acc[mt][nt][r] + bs;
        if (mode == 2) v = 0.5f * v * (1.0f + erff(v * 0.70710678118654752f));
        if (mode == 0) {
          if (col < SQK) {
            C[row * SQK + col] = f2b(v);
          } else {
            const int bb = (int)(row >> 11);
            const int ss = (int)(row & 2047);
            const int hh = (col - SQK) >> 6;
            const int ee = col & 63;
            // Vp[b][h][s/8][e][s&7]
            Vp[(((size_t)bb * H_ + hh) * 256 + (ss >> 3)) * 512 + ee * 8 + (ss & 7)] = f2b(v);
          }
        } else if (mode == 3) {
          Cf[row * (size_t)N + col] = v;
        } else {
          C[row * (size_t)N + col] = f2b(v);
        }
      }
    }
  }
}

// ---------------- flash attention: block = 128 q-rows of one (b,h), 4 waves ----------
// Fixed-base softmax (shift-invariant; base M0=12 safe for |s|<=~100):
//   p = exp2(fma(s_raw, log2e/8, -12*log2e));  l = sum(p) via MFMA ones-column.
// P buffer is per-wave private -> NO barriers in the K loop.
__global__ __launch_bounds__(256)
void attn_kernel(const bf16* __restrict__ QK, const bf16* __restrict__ Vp,
                 bf16* __restrict__ O)
{
  const int wave = threadIdx.x >> 6;
  const int lane = threadIdx.x & 63;
  const int l15 = lane & 15;
  const int qd  = lane >> 4;
  const int bh = blockIdx.y;
  const int b  = bh / H_;
  const int h  = bh % H_;
  const int q0 = blockIdx.x * 128 + wave * 32;   // this wave's first q-row

  const bf16* Qb = QK + (size_t)b * S_ * SQK + h * HD_;
  const bf16* Kb = Qb + D_;                       // K block lives at col+768
  const bf16* Vb = Vp + (size_t)bh * 256 * 512;

  uint4 qf[2][2];
#pragma unroll
  for (int mt = 0; mt < 2; ++mt)
#pragma unroll
    for (int ks = 0; ks < 2; ++ks)
      qf[mt][ks] = *(const uint4*)(Qb + (size_t)(q0 + mt * 16 + l15) * SQK + ks * 32 + qd * 8);

  f32x4 o_[2][5];                               // [.. ][4] = ones-column row-sums (l)
#pragma unroll
  for (int mt = 0; mt < 2; ++mt)
#pragma unroll
    for (int dt = 0; dt < 5; ++dt) o_[mt][dt] = zero4();

  // constant ones-column B fragment: B[k][n] = (n==0) ? 1 : 0
  uint4 vones;
  { const unsigned v = (l15 == 0) ? 0x3F803F80u : 0u; vones.x = v; vones.y = v; vones.z = v; vones.w = v; }

  // per-wave private P: 32 x 64 bf16, stride 88 u16 + row-bit3 bank offset (+16 u16)
  __shared__ __align__(16) unsigned short Pl[4][2848];
  unsigned short* Pw = &Pl[wave][0];

  const float C1 = 1.4426950408889634f * 0.125f;   // log2e / 8
  const float C0 = -12.0f * 1.4426950408889634f;   // -M0 * log2e

  for (int sk = 0; sk < S_; sk += 64) {
    // --- raw scores S = Q K^T (scale folded into exp) ---
    uint4 kf[2][4];
#pragma unroll
    for (int ks = 0; ks < 2; ++ks)
#pragma unroll
      for (int nt = 0; nt < 4; ++nt)
        kf[ks][nt] = *(const uint4*)(Kb + (size_t)(sk + nt * 16 + l15) * SQK + ks * 32 + qd * 8);
    f32x4 s[2][4];
#pragma unroll
    for (int mt = 0; mt < 2; ++mt)
#pragma unroll
      for (int nt = 0; nt < 4; ++nt) s[mt][nt] = zero4();
#pragma unroll
    for (int ks = 0; ks < 2; ++ks)
#pragma unroll
      for (int mt = 0; mt < 2; ++mt)
#pragma unroll
        for (int nt = 0; nt < 4; ++nt)
          s[mt][nt] = mfma16(qf[mt][ks], kf[ks][nt], s[mt][nt]);

    // --- p = exp2(fma(s,C1,C0)); write to P (C-layout -> LDS) ---
#pragma unroll
    for (int mt = 0; mt < 2; ++mt)
#pragma unroll
      for (int nt = 0; nt < 4; ++nt)
#pragma unroll
        for (int r = 0; r < 4; ++r) {
          const int row = mt * 16 + qd * 4 + r;
          const float p = exp2f(fmaf(s[mt][nt][r], C1, C0));
          Pw[row * 88 + ((row >> 3) & 1) * 16 + nt * 16 + l15] = f2bits(p);
        }

    // --- read P as A-fragments (same wave; DS in-order, no barrier needed) ---
    uint4 pf[2][2];
#pragma unroll
    for (int mt = 0; mt < 2; ++mt)
#pragma unroll
      for (int ks = 0; ks < 2; ++ks)
        pf[mt][ks] = *(const uint4*)(Pw + (mt * 16 + l15) * 88 + ((l15 >> 3) & 1) * 16 + ks * 32 + qd * 8);

    // --- O += P V ; l += P * ones ---
    uint4 vf[2][4];
#pragma unroll
    for (int ks = 0; ks < 2; ++ks)
#pragma unroll
      for (int dt = 0; dt < 4; ++dt)
        vf[ks][dt] = *(const uint4*)(Vb + ((size_t)(sk >> 3) + ks * 4 + qd) * 512 + (dt * 16 + l15) * 8);
#pragma unroll
    for (int ks = 0; ks < 2; ++ks)
#pragma unroll
      for (int mt = 0; mt < 2; ++mt) {
#pragma unroll
        for (int dt = 0; dt < 4; ++dt)
          o_[mt][dt] = mfma16(pf[mt][ks], vf[ks][dt], o_[mt][dt]);
        o_[mt][4] = mfma16(pf[mt][ks], vones, o_[mt][4]);
      }
  }

  // --- epilogue: O / l  -> o_buf[b, s, h*64 + e]; l lives on l15==0 lanes ---
  const size_t tok0 = (size_t)b * S_ + q0;
#pragma unroll
  for (int mt = 0; mt < 2; ++mt) {
#pragma unroll
    for (int r = 0; r < 4; ++r) {
      const float lr = __shfl(o_[mt][4][r], (lane & 48), 64);
      const float inv = 1.0f / lr;
      const size_t row = tok0 + mt * 16 + qd * 4 + r;
#pragma unroll
      for (int dt = 0; dt < 4; ++dt)
        O[row * D_ + h * HD_ + dt * 16 + l15] = f2b(o_[mt][dt][r] * inv);
    }
  }
}

// ---------------- orchestration ----------------
extern "C" void kernel_launch(void* const* d_in, const int* in_sizes, int n_in,
                              void* d_out, int out_size, void* d_ws, size_t ws_size,
                              hipStream_t stream)
{
  const float* x   = (const float*)d_in[0];
  const float* Wq  = (const float*)d_in[1];
  const float* bq  = (const float*)d_in[2];
  const float* Wk  = (const float*)d_in[3];
  const float* bk  = (const float*)d_in[4];
  const float* Wv  = (const float*)d_in[5];
  const float* bv  = (const float*)d_in[6];
  const float* Wo  = (const float*)d_in[7];
  const float* bo  = (const float*)d_in[8];
  const float* W1  = (const float*)d_in[9];
  const float* b1  = (const float*)d_in[10];
  const float* W2  = (const float*)d_in[11];
  const float* b2  = (const float*)d_in[12];
  const float* g1  = (const float*)d_in[13];
  const float* be1 = (const float*)d_in[14];
  const float* g2  = (const float*)d_in[15];
  const float* be2 = (const float*)d_in[16];

  // full-M FFN needs 77,079,552 B of workspace; otherwise split (64,496,640 B)
  const bool full = ws_size >= (size_t)77079552;

  char* ws = (char*)d_ws;
  bf16* qk     = (bf16*)(ws + 0);           // QKV gemm -> attn
  bf16* vp     = (bf16*)(ws + 25165824);    // QKV gemm -> attn
  bf16* h1     = (bf16*)(ws + 37748736);    // LN1 -> QKV gemm
  bf16* obuf   = h1;                        // attn -> O-proj (h1 dead)
  bf16* abuf   = (bf16*)(ws + 0);           // O-proj -> LN2 (qk dead)
  bf16* h2     = (bf16*)(ws + (full ? 50331648u : 25165824u));  // LN2 -> FFN1
  bf16* fbuf   = (bf16*)(ws + 0);           // FFN1 -> FFN2 (full: 48 MB; split: 24 MB)
  const size_t wb = full ? 62914560u : 50331648u;
  bf16* wqkv_p = (bf16*)(ws + wb);                    // 3,538,944 B
  bf16* wo_p   = (bf16*)(ws + wb + 3538944u);         // 1,179,648 B
  bf16* w1_p   = (bf16*)(ws + wb + 4718592u);         // 4,718,592 B
  bf16* w2_p   = (bf16*)(ws + wb + 9437184u);         // 4,718,592 B
  float* bqkvf = (float*)(ws + wb + 14155776u);       // 9,216 B

  repack_qkv_t<<<dim3(864),  dim3(256), 0, stream>>>(Wq, Wk, Wv, wqkv_p);
  repack_t    <<<dim3(288),  dim3(256), 0, stream>>>(Wo, wo_p, 768, 768);
  repack_t    <<<dim3(1152), dim3(256), 0, stream>>>(W1, w1_p, 768, 3072);
  repack_t    <<<dim3(1152), dim3(256), 0, stream>>>(W2, w2_p, 3072, 768);
  bias_qkv    <<<dim3(9),    dim3(256), 0, stream>>>(bq, bk, bv, bqkvf);

  ln_x_kernel<<<dim3(BS_), dim3(256), 0, stream>>>(x, g1, be1, h1);
  gemm_lds<<<dim3(18, 64), dim3(256), 0, stream>>>(h1, wqkv_p, bqkvf, qk, vp, nullptr, 768, 2304, 0);
  attn_kernel<<<dim3(16, 48), dim3(256), 0, stream>>>(qk, vp, obuf);
  gemm_lds<<<dim3(6, 64),  dim3(256), 0, stream>>>(obuf, wo_p, bo, abuf, nullptr, nullptr, 768, 768, 1);
  ln_h_kernel<<<dim3(BS_), dim3(256), 0, stream>>>(abuf, g2, be2, h2);

  float* outp = (float*)d_out;
  if (full) {
    gemm_lds<<<dim3(24, 64), dim3(256), 0, stream>>>(h2, w1_p, b1, fbuf, nullptr, nullptr, 768, 3072, 2);
    gemm_lds<<<dim3(6, 64),  dim3(256), 0, stream>>>(fbuf, w2_p, b2, nullptr, nullptr, outp, 3072, 768, 3);
  } else {
    gemm_lds<<<dim3(24, 32), dim3(256), 0, stream>>>(h2, w1_p, b1, fbuf, nullptr, nullptr, 768, 3072, 2);
    gemm_lds<<<dim3(6, 32),  dim3(256), 0, stream>>>(fbuf, w2_p, b2, nullptr, nullptr, outp, 3072, 768, 3);
    gemm_lds<<<dim3(24, 32), dim3(256), 0, stream>>>(h2 + (size_t)4096 * D_, w1_p, b1, fbuf, nullptr, nullptr, 768, 3072, 2);
    gemm_lds<<<dim3(6, 32),  dim3(256), 0, stream>>>(fbuf, w2_p, b2, nullptr, nullptr, outp + (size_t)4096 * D_, 3072, 768, 3);
  }
}

// Round 7
// 515.142 us; speedup vs baseline: 3.0614x; 1.0223x over previous
//
#include <hip/hip_runtime.h>
#include <hip/hip_bf16.h>
#include <math.h>

typedef __hip_bfloat16 bf16;
typedef __attribute__((ext_vector_type(8))) short short8;
typedef __attribute__((ext_vector_type(4))) float f32x4;

#define D_  768
#define H_  12
#define HD_ 64
#define F_  3072
#define B_  4
#define S_  2048
#define BS_ (B_*S_)
#define SQK 1536   // Q,K buffer row stride (V lives in packed Vp)
#define PSTR 72    // P LDS row stride in u16 (64 + 8 pad; 144 B = 16B-aligned rows)

__device__ __forceinline__ float b2f(bf16 x){ return __bfloat162float(x); }

union BU { bf16 b; unsigned short u; };
// fast bf16 round (half-away ties; inputs are finite, non-NaN)
__device__ __forceinline__ bf16 f2b_fast(float x){
  BU t; t.u = (unsigned short)((__float_as_uint(x) + 0x8000u) >> 16); return t.b;
}
// pack two floats -> bf16x2 dword (low u16 = a)
__device__ __forceinline__ unsigned pk2bf(float a, float b){
  return __builtin_amdgcn_perm(__float_as_uint(b) + 0x8000u,
                               __float_as_uint(a) + 0x8000u, 0x07060302u);
}

__device__ __forceinline__ f32x4 zero4(){ f32x4 z; z.x=0.f; z.y=0.f; z.z=0.f; z.w=0.f; return z; }

__device__ __forceinline__ f32x4 mfma16(uint4 a, uint4 b, f32x4 c){
  union U { uint4 u; short8 s; };
  U A, B; A.u = a; B.u = b;
  return __builtin_amdgcn_mfma_f32_16x16x32_bf16(A.s, B.s, c, 0, 0, 0);
}

// async global->LDS, 16 B per lane (global_load_lds_dwordx4)
typedef const __attribute__((address_space(1))) void gvoid;
typedef __attribute__((address_space(3))) void lvoid;
__device__ __forceinline__ void load_lds16(const void* g, void* l){
  __builtin_amdgcn_global_load_lds((gvoid*)g, (lvoid*)l, 16, 0, 0);
}

// exact-accuracy GELU via A&S 7.1.26 erf (|eps| <= 1.5e-7), HW exp/rcp
__device__ __forceinline__ float fast_gelu(float v){
  const float x = v * 0.70710678118654752f;
  const float ax = fabsf(x);
  const float t = __builtin_amdgcn_rcpf(fmaf(0.3275911f, ax, 1.0f));
  const float poly = t * fmaf(t, fmaf(t, fmaf(t, fmaf(t, 1.061405429f, -1.453152027f),
                                              1.421413741f), -0.284496736f), 0.254829592f);
  const float e = __builtin_amdgcn_exp2f(ax * ax * -1.4426950408889634f);
  const float erfax = 1.0f - poly * e;
  const float erfx = copysignf(erfax, x);
  return 0.5f * v * (1.0f + erfx);
}

// ---------------- weight repack (fp32 -> bf16 W^T): Wt[n][k] = W[k][n] -------------
__global__ __launch_bounds__(256)
void repack_t(const float* __restrict__ W, bf16* __restrict__ Wt, int K, int N)
{
  const int t = blockIdx.x * 256 + threadIdx.x;   // exact grids
  const int n = t % N;
  const int kg = t / N;
  const float* src = W + (size_t)kg * 8 * N + n;
  union { unsigned u32[4]; uint4 u; } pk;
#pragma unroll
  for (int j = 0; j < 4; ++j)
    pk.u32[j] = pk2bf(src[(size_t)(2 * j) * N], src[(size_t)(2 * j + 1) * N]);
  *(uint4*)(Wt + ((size_t)n * (K >> 3) + kg) * 8) = pk.u;
}

// QKV combined W^T: rows n in [0,2304): sel=n/768, h=(n%768)>>6, e=n&63; K=768
__global__ __launch_bounds__(256)
void repack_qkv_t(const float* __restrict__ Wq, const float* __restrict__ Wk,
                  const float* __restrict__ Wv, bf16* __restrict__ Wt)
{
  const int t = blockIdx.x * 256 + threadIdx.x;   // 864*256 = 96*2304 exact
  const int n = t % 2304;
  const int kg = t / 2304;                        // 0..95
  const int sel = n / 768;
  const int nn = n - sel * 768;
  const int hh = nn >> 6;
  const int ee = nn & 63;
  const float* W = (sel == 0) ? Wq : (sel == 1) ? Wk : Wv;
  const float* src = W + ((size_t)hh * 768 + (size_t)kg * 8) * 64 + ee;
  union { unsigned u32[4]; uint4 u; } pk;
#pragma unroll
  for (int j = 0; j < 4; ++j)
    pk.u32[j] = pk2bf(src[(size_t)(2 * j) * 64], src[(size_t)(2 * j + 1) * 64]);
  *(uint4*)(Wt + ((size_t)n * 96 + kg) * 8) = pk.u;
}

__global__ __launch_bounds__(256)
void bias_qkv(const float* __restrict__ bq, const float* __restrict__ bk,
              const float* __restrict__ bv, float* __restrict__ out)
{
  const int t = blockIdx.x * 256 + threadIdx.x;   // 9*256 = 2304 exact
  out[t] = (t < 768) ? bq[t] : (t < 1536) ? bk[t - 768] : bv[t - 1536];
}

// ---------------- LayerNorm: one block per token, 256 thr, D=768=256*3 ----------------
__global__ __launch_bounds__(256)
void ln_x_kernel(const float* __restrict__ X, const float* __restrict__ G,
                 const float* __restrict__ Bet, bf16* __restrict__ Y)
{
  const int t = threadIdx.x;
  const size_t row = blockIdx.x;
  const float* x = X + row * D_;
  float v0 = x[t], v1 = x[t + 256], v2 = x[t + 512];
  float s = v0 + v1 + v2;
#pragma unroll
  for (int d = 32; d >= 1; d >>= 1) s += __shfl_xor(s, d, 64);
  __shared__ float red[8];
  const int wv = t >> 6, ln = t & 63;
  if (ln == 0) red[wv] = s;
  __syncthreads();
  const float mu = (red[0] + red[1] + red[2] + red[3]) * (1.0f / 768.0f);
  const float d0 = v0 - mu, d1 = v1 - mu, d2 = v2 - mu;
  float sq = d0 * d0 + d1 * d1 + d2 * d2;
#pragma unroll
  for (int d = 32; d >= 1; d >>= 1) sq += __shfl_xor(sq, d, 64);
  if (ln == 0) red[4 + wv] = sq;
  __syncthreads();
  const float var = (red[4] + red[5] + red[6] + red[7]) * (1.0f / 768.0f);
  const float rs = rsqrtf(var + 1e-5f);
  bf16* y = Y + row * D_;
  y[t]       = f2b_fast(d0 * rs * G[t]       + Bet[t]);
  y[t + 256] = f2b_fast(d1 * rs * G[t + 256] + Bet[t + 256]);
  y[t + 512] = f2b_fast(d2 * rs * G[t + 512] + Bet[t + 512]);
}

__global__ __launch_bounds__(256)
void ln_h_kernel(const bf16* __restrict__ X, const float* __restrict__ G,
                 const float* __restrict__ Bet, bf16* __restrict__ Y)
{
  const int t = threadIdx.x;
  const size_t row = blockIdx.x;
  const bf16* x = X + row * D_;
  float v0 = b2f(x[t]), v1 = b2f(x[t + 256]), v2 = b2f(x[t + 512]);
  float s = v0 + v1 + v2;
#pragma unroll
  for (int d = 32; d >= 1; d >>= 1) s += __shfl_xor(s, d, 64);
  __shared__ float red[8];
  const int wv = t >> 6, ln = t & 63;
  if (ln == 0) red[wv] = s;
  __syncthreads();
  const float mu = (red[0] + red[1] + red[2] + red[3]) * (1.0f / 768.0f);
  const float d0 = v0 - mu, d1 = v1 - mu, d2 = v2 - mu;
  float sq = d0 * d0 + d1 * d1 + d2 * d2;
#pragma unroll
  for (int d = 32; d >= 1; d >>= 1) sq += __shfl_xor(sq, d, 64);
  if (ln == 0) red[4 + wv] = sq;
  __syncthreads();
  const float var = (red[4] + red[5] + red[6] + red[7]) * (1.0f / 768.0f);
  const float rs = rsqrtf(var + 1e-5f);
  bf16* y = Y + row * D_;
  y[t]       = f2b_fast(d0 * rs * G[t]       + Bet[t]);
  y[t + 256] = f2b_fast(d1 * rs * G[t + 256] + Bet[t + 256]);
  y[t + 512] = f2b_fast(d2 * rs * G[t + 512] + Bet[t + 512]);
}

// ------------- m97-style LDS-staged GEMM, C^T accumulation -------------------------
// acc[nt][mt] = Wt-tile x A-tile  (D rows = output col n, D cols = token m)
// -> each lane holds 4 CONSECUTIVE output cols => b64 / dwordx4 epilogue stores.
// modes: 0 QKV epilogue (qk/Vp), 1 bf16 C, 2 GELU bf16 C, 3 fp32 Cf
__global__ __launch_bounds__(256)
void gemm_lds(const bf16* __restrict__ A, const bf16* __restrict__ Wt,
              const float* __restrict__ bias, bf16* __restrict__ C,
              bf16* __restrict__ Vp, float* __restrict__ Cf,
              int K, int N, int mode)
{
  __shared__ __align__(16) bf16 As[128 * 32];   // [row][k], 64 B rows
  __shared__ __align__(16) bf16 Bs[128 * 32];

  const int tid = threadIdx.x;
  const int wave = tid >> 6, lane = tid & 63;
  const int l15 = lane & 15, qd = lane >> 4;
  const int wy = wave >> 1, wx = wave & 1;
  const size_t m0 = (size_t)blockIdx.y * 128;
  const int n0 = blockIdx.x * 128;

  const int r0 = tid >> 2, c0 = tid & 3;        // row 0..63, kchunk 0..3
  const bf16* Ag0 = A  + (m0 + r0) * (size_t)K + c0 * 8;
  const bf16* Ag1 = A  + (m0 + r0 + 64) * (size_t)K + c0 * 8;
  const bf16* Bg0 = Wt + (size_t)(n0 + r0) * K + c0 * 8;
  const bf16* Bg1 = Wt + (size_t)(n0 + r0 + 64) * K + c0 * 8;
  bf16* Al0 = As + (size_t)tid * 8;
  bf16* Al1 = As + (size_t)(tid + 256) * 8;
  bf16* Bl0 = Bs + (size_t)tid * 8;
  bf16* Bl1 = Bs + (size_t)(tid + 256) * 8;

  f32x4 acc[4][4];                               // [nt][mt]
#pragma unroll
  for (int i = 0; i < 4; ++i)
#pragma unroll
    for (int j = 0; j < 4; ++j) acc[i][j] = zero4();

  const int arow = wy * 64;
  const int brow = wx * 64;

  for (int k0 = 0; k0 < K; k0 += 32) {
    load_lds16(Ag0 + k0, Al0);
    load_lds16(Ag1 + k0, Al1);
    load_lds16(Bg0 + k0, Bl0);
    load_lds16(Bg1 + k0, Bl1);
    __syncthreads();
    uint4 af[4], bfr[4];
#pragma unroll
    for (int mt = 0; mt < 4; ++mt)
      af[mt] = *(const uint4*)(As + (size_t)(arow + mt * 16 + l15) * 32 + qd * 8);
#pragma unroll
    for (int nt = 0; nt < 4; ++nt)
      bfr[nt] = *(const uint4*)(Bs + (size_t)(brow + nt * 16 + l15) * 32 + qd * 8);
#pragma unroll
    for (int nt = 0; nt < 4; ++nt)
#pragma unroll
      for (int mt = 0; mt < 4; ++mt)
        acc[nt][mt] = mfma16(bfr[nt], af[mt], acc[nt][mt]);   // C^T
    __syncthreads();
  }

  // epilogue: D row = out col n = brow+nt*16+qd*4+r (4 consecutive), D col = token m
  const size_t wm0 = m0 + arow;
  const int wn0 = n0 + brow;
#pragma unroll
  for (int nt = 0; nt < 4; ++nt) {
    const int nb = wn0 + nt * 16 + qd * 4;
    const f32x4 bs4 = *(const f32x4*)(bias + nb);
#pragma unroll
    for (int mt = 0; mt < 4; ++mt) {
      const size_t m = wm0 + mt * 16 + l15;
      float v[4];
#pragma unroll
      for (int r = 0; r < 4; ++r) v[r] = acc[nt][mt][r] + bs4[r];
      if (mode == 2) {
#pragma unroll
        for (int r = 0; r < 4; ++r) v[r] = fast_gelu(v[r]);
      }
      if (mode == 3) {
        f32x4 o; o.x = v[0]; o.y = v[1]; o.z = v[2]; o.w = v[3];
        *(f32x4*)(Cf + m * (size_t)N + nb) = o;
      } else if (mode == 0) {
        if (nb < SQK) {
          uint2 w; w.x = pk2bf(v[0], v[1]); w.y = pk2bf(v[2], v[3]);
          *(uint2*)(C + m * SQK + nb) = w;
        } else {
          const int bb = (int)(m >> 11);
          const int ss = (int)(m & 2047);
          const int hh = (nb - SQK) >> 6;
          const size_t vbase = (((size_t)bb * H_ + hh) * 256 + (ss >> 3)) * 512 + (ss & 7);
#pragma unroll
          for (int r = 0; r < 4; ++r)
            Vp[vbase + (size_t)((nb & 63) + r) * 8] = f2b_fast(v[r]);   // Vp[b][h][s/8][e][s&7]
        }
      } else {
        uint2 w; w.x = pk2bf(v[0], v[1]); w.y = pk2bf(v[2], v[3]);
        *(uint2*)(C + m * (size_t)N + nb) = w;
      }
    }
  }
}

// ---------------- flash attention: block = 128 q-rows of one (b,h), 4 waves ----------
// S^T = K·Q^T (swapped operands): lanes hold 4 CONSECUTIVE keys -> b64 P-writes into
// [q][key] LDS; PV A-frag reads stay ds_read_b128. Fixed-base softmax, l via ones-MFMA.
// P buffer per-wave private -> no barriers.
__global__ __launch_bounds__(256)
void attn_kernel(const bf16* __restrict__ QK, const bf16* __restrict__ Vp,
                 bf16* __restrict__ O)
{
  const int wave = threadIdx.x >> 6;
  const int lane = threadIdx.x & 63;
  const int l15 = lane & 15;
  const int qd  = lane >> 4;
  const int bh = blockIdx.y;
  const int b  = bh / H_;
  const int h  = bh % H_;
  const int q0 = blockIdx.x * 128 + wave * 32;   // this wave's first q-row

  const bf16* Qb = QK + (size_t)b * S_ * SQK + h * HD_;
  const bf16* Kb = Qb + D_;                       // K block lives at col+768
  const bf16* Vb = Vp + (size_t)bh * 256 * 512;

  uint4 qf[2][2];
#pragma unroll
  for (int mt = 0; mt < 2; ++mt)
#pragma unroll
    for (int ks = 0; ks < 2; ++ks)
      qf[mt][ks] = *(const uint4*)(Qb + (size_t)(q0 + mt * 16 + l15) * SQK + ks * 32 + qd * 8);

  f32x4 o_[2][5];                               // [..][4] = ones-column row-sums (l)
#pragma unroll
  for (int mt = 0; mt < 2; ++mt)
#pragma unroll
    for (int dt = 0; dt < 5; ++dt) o_[mt][dt] = zero4();

  // constant ones-column B fragment: B[k][n] = (n==0) ? 1 : 0
  uint4 vones;
  { const unsigned v = (l15 == 0) ? 0x3F803F80u : 0u; vones.x = v; vones.y = v; vones.z = v; vones.w = v; }

  // per-wave private P: 32 q-rows x 64 keys bf16, row stride PSTR=72 u16 (16B rows)
  __shared__ __align__(16) unsigned short Pl[4][32 * PSTR];
  unsigned short* Pw = &Pl[wave][0];

  const float C1 = 1.4426950408889634f * 0.125f;   // log2e / 8
  const float C0 = -12.0f * 1.4426950408889634f;   // -M0 * log2e

  for (int sk = 0; sk < S_; sk += 64) {
    // --- K A-frags (rows = keys) ---
    uint4 kf[4][2];
#pragma unroll
    for (int kt = 0; kt < 4; ++kt)
#pragma unroll
      for (int ks = 0; ks < 2; ++ks)
        kf[kt][ks] = *(const uint4*)(Kb + (size_t)(sk + kt * 16 + l15) * SQK + ks * 32 + qd * 8);

    // --- S^T[key][q] = K·Q^T ---
    f32x4 st[4][2];
#pragma unroll
    for (int kt = 0; kt < 4; ++kt)
#pragma unroll
      for (int mt = 0; mt < 2; ++mt) st[kt][mt] = zero4();
#pragma unroll
    for (int ks = 0; ks < 2; ++ks)
#pragma unroll
      for (int kt = 0; kt < 4; ++kt)
#pragma unroll
        for (int mt = 0; mt < 2; ++mt)
          st[kt][mt] = mfma16(kf[kt][ks], qf[mt][ks], st[kt][mt]);

    // --- p = exp2(fma(s,C1,C0)); 4 consecutive keys/lane -> one b64 LDS write ---
#pragma unroll
    for (int mt = 0; mt < 2; ++mt) {
      unsigned short* prow = Pw + (mt * 16 + l15) * PSTR;
#pragma unroll
      for (int kt = 0; kt < 4; ++kt) {
        const float p0 = __builtin_amdgcn_exp2f(fmaf(st[kt][mt][0], C1, C0));
        const float p1 = __builtin_amdgcn_exp2f(fmaf(st[kt][mt][1], C1, C0));
        const float p2 = __builtin_amdgcn_exp2f(fmaf(st[kt][mt][2], C1, C0));
        const float p3 = __builtin_amdgcn_exp2f(fmaf(st[kt][mt][3], C1, C0));
        uint2 w; w.x = pk2bf(p0, p1); w.y = pk2bf(p2, p3);
        *(uint2*)(prow + kt * 16 + qd * 4) = w;
      }
    }

    // --- read P as A-fragments (same wave; DS in-order, no barrier needed) ---
    uint4 pf[2][2];
#pragma unroll
    for (int mt = 0; mt < 2; ++mt)
#pragma unroll
      for (int ks = 0; ks < 2; ++ks)
        pf[mt][ks] = *(const uint4*)(Pw + (mt * 16 + l15) * PSTR + ks * 32 + qd * 8);

    // --- O += P V ; l += P * ones ---
    uint4 vf[2][4];
#pragma unroll
    for (int ks = 0; ks < 2; ++ks)
#pragma unroll
      for (int dt = 0; dt < 4; ++dt)
        vf[ks][dt] = *(const uint4*)(Vb + ((size_t)(sk >> 3) + ks * 4 + qd) * 512 + (dt * 16 + l15) * 8);
#pragma unroll
    for (int ks = 0; ks < 2; ++ks)
#pragma unroll
      for (int mt = 0; mt < 2; ++mt) {
#pragma unroll
        for (int dt = 0; dt < 4; ++dt)
          o_[mt][dt] = mfma16(pf[mt][ks], vf[ks][dt], o_[mt][dt]);
        o_[mt][4] = mfma16(pf[mt][ks], vones, o_[mt][4]);
      }
  }

  // --- epilogue: O / l  -> o_buf[b, s, h*64 + e]; l lives on l15==0 lanes ---
  const size_t tok0 = (size_t)b * S_ + q0;
#pragma unroll
  for (int mt = 0; mt < 2; ++mt) {
#pragma unroll
    for (int r = 0; r < 4; ++r) {
      const float lr = __shfl(o_[mt][4][r], (lane & 48), 64);
      const float inv = __builtin_amdgcn_rcpf(lr);
      const size_t row = tok0 + mt * 16 + qd * 4 + r;
#pragma unroll
      for (int dt = 0; dt < 4; ++dt)
        O[row * D_ + h * HD_ + dt * 16 + l15] = f2b_fast(o_[mt][dt][r] * inv);
    }
  }
}

// ---------------- orchestration ----------------
extern "C" void kernel_launch(void* const* d_in, const int* in_sizes, int n_in,
                              void* d_out, int out_size, void* d_ws, size_t ws_size,
                              hipStream_t stream)
{
  const float* x   = (const float*)d_in[0];
  const float* Wq  = (const float*)d_in[1];
  const float* bq  = (const float*)d_in[2];
  const float* Wk  = (const float*)d_in[3];
  const float* bk  = (const float*)d_in[4];
  const float* Wv  = (const float*)d_in[5];
  const float* bv  = (const float*)d_in[6];
  const float* Wo  = (const float*)d_in[7];
  const float* bo  = (const float*)d_in[8];
  const float* W1  = (const float*)d_in[9];
  const float* b1  = (const float*)d_in[10];
  const float* W2  = (const float*)d_in[11];
  const float* b2  = (const float*)d_in[12];
  const float* g1  = (const float*)d_in[13];
  const float* be1 = (const float*)d_in[14];
  const float* g2  = (const float*)d_in[15];
  const float* be2 = (const float*)d_in[16];

  // full-M FFN needs 77,079,552 B of workspace; otherwise split (64,496,640 B)
  const bool full = ws_size >= (size_t)77079552;

  char* ws = (char*)d_ws;
  bf16* qk     = (bf16*)(ws + 0);           // QKV gemm -> attn
  bf16* vp     = (bf16*)(ws + 25165824);    // QKV gemm -> attn
  bf16* h1     = (bf16*)(ws + 37748736);    // LN1 -> QKV gemm
  bf16* obuf   = h1;                        // attn -> O-proj (h1 dead)
  bf16* abuf   = (bf16*)(ws + 0);           // O-proj -> LN2 (qk dead)
  bf16* h2     = (bf16*)(ws + (full ? 50331648u : 25165824u));  // LN2 -> FFN1
  bf16* fbuf   = (bf16*)(ws + 0);           // FFN1 -> FFN2 (full: 48 MB; split: 24 MB)
  const size_t wb = full ? 62914560u : 50331648u;
  bf16* wqkv_p = (bf16*)(ws + wb);                    // 3,538,944 B
  bf16* wo_p   = (bf16*)(ws + wb + 3538944u);         // 1,179,648 B
  bf16* w1_p   = (bf16*)(ws + wb + 4718592u);         // 4,718,592 B
  bf16* w2_p   = (bf16*)(ws + wb + 9437184u);         // 4,718,592 B
  float* bqkvf = (float*)(ws + wb + 14155776u);       // 9,216 B

  repack_qkv_t<<<dim3(864),  dim3(256), 0, stream>>>(Wq, Wk, Wv, wqkv_p);
  repack_t    <<<dim3(288),  dim3(256), 0, stream>>>(Wo, wo_p, 768, 768);
  repack_t    <<<dim3(1152), dim3(256), 0, stream>>>(W1, w1_p, 768, 3072);
  repack_t    <<<dim3(1152), dim3(256), 0, stream>>>(W2, w2_p, 3072, 768);
  bias_qkv    <<<dim3(9),    dim3(256), 0, stream>>>(bq, bk, bv, bqkvf);

  ln_x_kernel<<<dim3(BS_), dim3(256), 0, stream>>>(x, g1, be1, h1);
  gemm_lds<<<dim3(18, 64), dim3(256), 0, stream>>>(h1, wqkv_p, bqkvf, qk, vp, nullptr, 768, 2304, 0);
  attn_kernel<<<dim3(16, 48), dim3(256), 0, stream>>>(qk, vp, obuf);
  gemm_lds<<<dim3(6, 64),  dim3(256), 0, stream>>>(obuf, wo_p, bo, abuf, nullptr, nullptr, 768, 768, 1);
  ln_h_kernel<<<dim3(BS_), dim3(256), 0, stream>>>(abuf, g2, be2, h2);

  float* outp = (float*)d_out;
  if (full) {
    gemm_lds<<<dim3(24, 64), dim3(256), 0, stream>>>(h2, w1_p, b1, fbuf, nullptr, nullptr, 768, 3072, 2);
    gemm_lds<<<dim3(6, 64),  dim3(256), 0, stream>>>(fbuf, w2_p, b2, nullptr, nullptr, outp, 3072, 768, 3);
  } else {
    gemm_lds<<<dim3(24, 32), dim3(256), 0, stream>>>(h2, w1_p, b1, fbuf, nullptr, nullptr, 768, 3072, 2);
    gemm_lds<<<dim3(6, 32),  dim3(256), 0, stream>>>(fbuf, w2_p, b2, nullptr, nullptr, outp, 3072, 768, 3);
    gemm_lds<<<dim3(24, 32), dim3(256), 0, stream>>>(h2 + (size_t)4096 * D_, w1_p, b1, fbuf, nullptr, nullptr, 768, 3072, 2);
    gemm_lds<<<dim3(6, 32),  dim3(256), 0, stream>>>(fbuf, w2_p, b2, nullptr, nullptr, outp + (size_t)4096 * D_, 3072, 768, 3);
  }
}